// Round 1
// baseline (491.318 us; speedup 1.0000x reference)
//
#include <hip/hip_runtime.h>
#include <math.h>

#define Mv 8
#define Nv 8192
#define Kv 256
#define BPM 64           // blocks per m in p1 -> 512 blocks total
#define NITER 6
#define EPSILON_C 0.01f
#define GAMMA_C 0.005f

// ws layout (float offsets)
#define WS_R    0        // 72   (M x 3 x 3 row-major)
#define WS_T    72       // 24   (M x 3)
#define WS_X    96       // 768  (K x 3)
#define WS_Q    864      // 256
#define WS_BETA 1120     // 1
#define WS_L    1124     // 2048 (M x K)
#define WS_W    3172     // 6144 (M x 3 x K)  -- raw (no Q scaling)
#define WS_H    9316     // 2048 (M x K)
#define WS_ZERO_N (2048+6144+2048)

// ---------------------------------------------------------------- init
__global__ __launch_bounds__(256) void p0_init(const float* __restrict__ Vs,
                                               const float* __restrict__ X0,
                                               const float* __restrict__ Q0,
                                               float* __restrict__ ws) {
  __shared__ float sred[4];
  int tid = threadIdx.x;
  int b = blockIdx.x;
  if (b < 24) {
    int m = b / 3, d = b % 3;
    const float* src = Vs + (size_t)(m*3 + d) * Nv;
    float s = 0.f;
    for (int n = tid; n < Nv; n += 256) s += src[n];
    for (int off = 32; off > 0; off >>= 1) s += __shfl_xor(s, off, 64);
    int wave = tid >> 6, lane = tid & 63;
    if (lane == 0) sred[wave] = s;
    __syncthreads();
    if (tid == 0) {
      float tot = sred[0]+sred[1]+sred[2]+sred[3];
      ws[WS_T + m*3 + d] = -tot / (float)Nv;
    }
    if (d == 0 && tid < 9) {
      ws[WS_R + m*9 + tid] = (tid==0||tid==4||tid==8) ? 1.f : 0.f;
    }
  } else {
    float s = (tid < Kv) ? Q0[tid] : 0.f;
    for (int off = 32; off > 0; off >>= 1) s += __shfl_xor(s, off, 64);
    int wave = tid >> 6, lane = tid & 63;
    if (lane == 0) sred[wave] = s;
    __syncthreads();
    if (tid == 0) {
      float mq = (sred[0]+sred[1]+sred[2]+sred[3]) / (float)Kv;
      ws[WS_BETA] = GAMMA_C * mq * sqrtf(mq);
    }
    if (tid < Kv) ws[WS_Q + tid] = Q0[tid];
    for (int i = tid; i < Kv*3; i += 256) ws[WS_X + i] = X0[i];
    for (int i = tid; i < WS_ZERO_N; i += 256) ws[WS_L + i] = 0.f;
  }
}

// ------------------------------------------------- big fused pass (per iter)
// One wave per point; lane l owns k in {l, l+64, l+128, l+192}.
// Accumulates L, Wraw, H in registers; block reduce; atomicAdd to ws.
__global__ __launch_bounds__(256) void p1_accum(const float* __restrict__ Vs,
                                                float* __restrict__ ws) {
  __shared__ float sb[4][5][Kv]; // 20 KB
  int m    = blockIdx.x / BPM;
  int blk  = blockIdx.x % BPM;
  int wave = threadIdx.x >> 6;
  int lane = threadIdx.x & 63;
  int wid  = blk*4 + wave;   // 0..255 within this m

  float R00 = ws[WS_R+m*9+0], R01 = ws[WS_R+m*9+1], R02 = ws[WS_R+m*9+2];
  float R10 = ws[WS_R+m*9+3], R11 = ws[WS_R+m*9+4], R12 = ws[WS_R+m*9+5];
  float R20 = ws[WS_R+m*9+6], R21 = ws[WS_R+m*9+7], R22 = ws[WS_R+m*9+8];
  float t0 = ws[WS_T+m*3+0], t1 = ws[WS_T+m*3+1], t2 = ws[WS_T+m*3+2];
  float beta = ws[WS_BETA];

  float kXx[4],kXy[4],kXz[4],kA[4],kB[4],kQ[4],kQ32[4];
  #pragma unroll
  for (int j=0;j<4;j++) {
    int k = lane + 64*j;
    float xx = ws[WS_X+k*3+0], xy = ws[WS_X+k*3+1], xz = ws[WS_X+k*3+2];
    float q  = ws[WS_Q+k];
    kXx[j]=xx; kXy[j]=xy; kXz[j]=xz;
    kA[j]  = -0.5f*q;
    kB[j]  = kA[j]*(xx*xx+xy*xy+xz*xz);
    kQ[j]  = q;
    kQ32[j]= q*sqrtf(q);
  }
  float aL[4]={0,0,0,0}, aWx[4]={0,0,0,0}, aWy[4]={0,0,0,0},
        aWz[4]={0,0,0,0}, aH[4]={0,0,0,0};
  const float* V0 = Vs + (size_t)(m*3+0)*Nv;
  const float* V1 = Vs + (size_t)(m*3+1)*Nv;
  const float* V2 = Vs + (size_t)(m*3+2)*Nv;

  for (int n = wid; n < Nv; n += 256) {
    float vx = V0[n], vy = V1[n], vz = V2[n];
    float px = fmaf(R00,vx, fmaf(R01,vy, fmaf(R02,vz, t0)));
    float py = fmaf(R10,vx, fmaf(R11,vy, fmaf(R12,vz, t1)));
    float pz = fmaf(R20,vx, fmaf(R21,vy, fmaf(R22,vz, t2)));
    float tvn = fmaf(px,px, fmaf(py,py, pz*pz));
    float vn  = fmaf(vx,vx, fmaf(vy,vy, vz*vz));
    float ap[4]; float s = 0.f;
    #pragma unroll
    for (int j=0;j<4;j++) {
      float dot = fmaf(px,kXx[j], fmaf(py,kXy[j], pz*kXz[j]));
      // arg = -0.5*Q*(tvn + xn - 2*dot)
      float arg = fmaf(kQ[j], dot, fmaf(kA[j], tvn, kB[j]));
      float e = __expf(arg)*kQ32[j];
      ap[j] = e; s += e;
    }
    #pragma unroll
    for (int off=32; off>0; off>>=1) s += __shfl_xor(s, off, 64);
    float inv = 1.f/(s + beta);
    #pragma unroll
    for (int j=0;j<4;j++) {
      float a = ap[j]*inv;
      aL[j] += a;
      aWx[j] = fmaf(a,vx,aWx[j]);
      aWy[j] = fmaf(a,vy,aWy[j]);
      aWz[j] = fmaf(a,vz,aWz[j]);
      aH[j]  = fmaf(a,vn,aH[j]);
    }
  }
  #pragma unroll
  for (int j=0;j<4;j++) {
    int k = lane + 64*j;
    sb[wave][0][k]=aL[j];  sb[wave][1][k]=aWx[j]; sb[wave][2][k]=aWy[j];
    sb[wave][3][k]=aWz[j]; sb[wave][4][k]=aH[j];
  }
  __syncthreads();
  int k = threadIdx.x;
  float vL  = sb[0][0][k]+sb[1][0][k]+sb[2][0][k]+sb[3][0][k];
  float vWx = sb[0][1][k]+sb[1][1][k]+sb[2][1][k]+sb[3][1][k];
  float vWy = sb[0][2][k]+sb[1][2][k]+sb[2][2][k]+sb[3][2][k];
  float vWz = sb[0][3][k]+sb[1][3][k]+sb[2][3][k]+sb[3][3][k];
  float vH  = sb[0][4][k]+sb[1][4][k]+sb[2][4][k]+sb[3][4][k];
  atomicAdd(&ws[WS_L + m*Kv + k], vL);
  atomicAdd(&ws[WS_W + (m*3+0)*Kv + k], vWx);
  atomicAdd(&ws[WS_W + (m*3+1)*Kv + k], vWy);
  atomicAdd(&ws[WS_W + (m*3+2)*Kv + k], vWz);
  atomicAdd(&ws[WS_H + m*Kv + k], vH);
}

// ---------------------------------------------------------------- 3x3 SVD->R
__device__ inline void svd3_rot(const double P[3][3], double R[3][3]) {
  double A[3][3];
  for (int i=0;i<3;i++) for (int j=0;j<3;j++) {
    double s=0; for (int k=0;k<3;k++) s += P[k][i]*P[k][j];
    A[i][j]=s;
  }
  double V[3][3] = {{1,0,0},{0,1,0},{0,0,1}};
  for (int it=0; it<30; it++) {
    int r3 = it % 3;
    int p = (r3==2) ? 1 : 0;
    int q = (r3==0) ? 1 : 2;
    double apq = A[p][q];
    if (fabs(apq) < 1e-300) continue;
    double tau = (A[q][q]-A[p][p])/(2.0*apq);
    double tt = (tau>=0.0) ? 1.0/(tau + sqrt(1.0+tau*tau))
                           : 1.0/(tau - sqrt(1.0+tau*tau));
    double c = 1.0/sqrt(1.0+tt*tt), s = tt*c;
    for (int k2=0;k2<3;k2++){ double akp=A[k2][p], akq=A[k2][q];
      A[k2][p]=c*akp - s*akq; A[k2][q]=s*akp + c*akq; }
    for (int k2=0;k2<3;k2++){ double apk=A[p][k2], aqk=A[q][k2];
      A[p][k2]=c*apk - s*aqk; A[q][k2]=s*apk + c*aqk; }
    for (int k2=0;k2<3;k2++){ double vkp=V[k2][p], vkq=V[k2][q];
      V[k2][p]=c*vkp - s*vkq; V[k2][q]=s*vkp + c*vkq; }
  }
  double lam[3] = {A[0][0], A[1][1], A[2][2]};
  int idx[3] = {0,1,2};
  for (int i=0;i<2;i++) for (int j=i+1;j<3;j++)
    if (lam[idx[j]] > lam[idx[i]]) { int tmp=idx[i]; idx[i]=idx[j]; idx[j]=tmp; }
  double v[3][3]; // v[c][i] = column c of V
  for (int c=0;c<3;c++) for (int i=0;i<3;i++) v[c][i] = V[i][idx[c]];
  double sv[3];
  for (int c=0;c<3;c++) { double l = lam[idx[c]]; sv[c] = (l>0.0) ? sqrt(l) : 0.0; }
  if (sv[0] <= 1e-150) { // P ~ 0: degenerate, return identity
    for (int i=0;i<3;i++) for (int j=0;j<3;j++) R[i][j] = (i==j)?1.0:0.0;
    return;
  }
  double u[3][3]; int bad2 = 0;
  for (int c=0;c<3;c++) {
    double uc[3];
    for (int i=0;i<3;i++) uc[i] = P[i][0]*v[c][0] + P[i][1]*v[c][1] + P[i][2]*v[c][2];
    if (sv[c] > 1e-12*sv[0]) {
      for (int i=0;i<3;i++) u[c][i] = uc[i]/sv[c];
    } else {
      if (c == 1) { // rank-1: pick any unit vector orthogonal to u0
        double ax[3] = {1,0,0};
        if (fabs(u[0][0]) > 0.9) { ax[0]=0; ax[1]=1; }
        double cx0 = u[0][1]*ax[2]-u[0][2]*ax[1];
        double cx1 = u[0][2]*ax[0]-u[0][0]*ax[2];
        double cx2 = u[0][0]*ax[1]-u[0][1]*ax[0];
        double nn = sqrt(cx0*cx0+cx1*cx1+cx2*cx2);
        u[1][0]=cx0/nn; u[1][1]=cx1/nn; u[1][2]=cx2/nn;
      } else if (c == 2) {
        bad2 = 1;
      }
    }
  }
  if (bad2) {
    double cx0 = u[0][1]*u[1][2]-u[0][2]*u[1][1];
    double cx1 = u[0][2]*u[1][0]-u[0][0]*u[1][2];
    double cx2 = u[0][0]*u[1][1]-u[0][1]*u[1][0];
    double nn = sqrt(cx0*cx0+cx1*cx1+cx2*cx2);
    u[2][0]=cx0/nn; u[2][1]=cx1/nn; u[2][2]=cx2/nn;
  }
  double detU = u[0][0]*(u[1][1]*u[2][2]-u[1][2]*u[2][1])
              - u[1][0]*(u[0][1]*u[2][2]-u[0][2]*u[2][1])
              + u[2][0]*(u[0][1]*u[1][2]-u[0][2]*u[1][1]);
  double detV = v[0][0]*(v[1][1]*v[2][2]-v[1][2]*v[2][1])
              - v[1][0]*(v[0][1]*v[2][2]-v[0][2]*v[2][1])
              + v[2][0]*(v[0][1]*v[1][2]-v[0][2]*v[1][1]);
  double sgn = (detU*detV >= 0.0) ? 1.0 : -1.0;
  for (int i=0;i<3;i++) for (int j=0;j<3;j++)
    R[i][j] = u[0][i]*v[0][j] + u[1][i]*v[1][j] + sgn*u[2][i]*v[2][j];
}

// --------------------------------------- per-iteration small update (1 block)
__global__ __launch_bounds__(256) void p2_update(float* __restrict__ ws, int iter) {
  __shared__ float sL[Mv][Kv];
  __shared__ float sW[Mv][3][Kv];
  __shared__ float sH[Mv][Kv];
  __shared__ float sX[Kv][3];
  __shared__ float sQ[Kv];
  __shared__ float sStats[Mv][16];
  __shared__ float swred[4][16];
  __shared__ float sR[Mv][9];
  __shared__ float sT[Mv][3];
  __shared__ float sTn[Mv];

  int tid = threadIdx.x;
  float* Lg = ws + WS_L;
  for (int i = tid; i < Mv*Kv;   i += 256) ((float*)sL)[i] = Lg[i];
  for (int i = tid; i < Mv*3*Kv; i += 256) ((float*)sW)[i] = (ws+WS_W)[i];
  for (int i = tid; i < Mv*Kv;   i += 256) ((float*)sH)[i] = (ws+WS_H)[i];
  sQ[tid]    = ws[WS_Q + tid];
  sX[tid][0] = ws[WS_X + tid*3+0];
  sX[tid][1] = ws[WS_X + tid*3+1];
  sX[tid][2] = ws[WS_X + tid*3+2];
  __syncthreads();
  // zero accumulators for next p1
  for (int i = tid; i < WS_ZERO_N; i += 256) Lg[i] = 0.f;

  int wave = tid >> 6, lane = tid & 63;
  for (int m = 0; m < Mv; m++) {
    int k = tid;
    float lk = sL[m][k], q = sQ[k];
    float bk = lk*q;
    float w0 = sW[m][0][k]*q, w1 = sW[m][1][k]*q, w2 = sW[m][2][k]*q;
    float x0 = sX[k][0], x1 = sX[k][1], x2 = sX[k][2];
    float pr[16];
    pr[0]=bk;  pr[1]=bk*x0; pr[2]=bk*x1; pr[3]=bk*x2;
    pr[4]=w0;  pr[5]=w1;    pr[6]=w2;
    pr[7]=w0*x0;  pr[8]=w1*x0;  pr[9]=w2*x0;
    pr[10]=w0*x1; pr[11]=w1*x1; pr[12]=w2*x1;
    pr[13]=w0*x2; pr[14]=w1*x2; pr[15]=w2*x2;
    #pragma unroll
    for (int v2=0; v2<16; v2++)
      #pragma unroll
      for (int off=32; off>0; off>>=1) pr[v2] += __shfl_xor(pr[v2], off, 64);
    if (lane == 0) {
      #pragma unroll
      for (int v2=0; v2<16; v2++) swred[wave][v2] = pr[v2];
    }
    __syncthreads();
    if (tid < 16) sStats[m][tid] = swred[0][tid]+swred[1][tid]+swred[2][tid]+swred[3][tid];
    __syncthreads();
  }
  if (tid < Mv) {
    int m = tid;
    double z = sStats[m][0];
    double mX[3] = {sStats[m][1], sStats[m][2], sStats[m][3]};
    double mW[3] = {sStats[m][4], sStats[m][5], sStats[m][6]};
    double Pm[3][3];
    for (int e=0;e<3;e++) for (int d=0;d<3;d++)
      Pm[e][d] = (double)sStats[m][7+e*3+d] - mX[e]*mW[d]/z;
    double Rm[3][3];
    svd3_rot(Pm, Rm);
    double tm[3];
    for (int i2=0;i2<3;i2++)
      tm[i2] = (mX[i2] - (Rm[i2][0]*mW[0]+Rm[i2][1]*mW[1]+Rm[i2][2]*mW[2]))/z;
    float tn = 0.f;
    for (int i2=0;i2<3;i2++) {
      for (int j2=0;j2<3;j2++) {
        float rv = (float)Rm[i2][j2];
        sR[m][i2*3+j2] = rv; ws[WS_R+m*9+i2*3+j2] = rv;
      }
      float tv = (float)tm[i2];
      sT[m][i2] = tv; ws[WS_T+m*3+i2] = tv;
      tn += tv*tv;
    }
    sTn[m] = tn;
  }
  __syncthreads();
  {
    int k = tid;
    float den = 0.f, Xn0=0.f, Xn1=0.f, Xn2=0.f, S2=0.f;
    #pragma unroll
    for (int m=0;m<Mv;m++) {
      float lk = sL[m][k];
      float w0 = sW[m][0][k], w1 = sW[m][1][k], w2 = sW[m][2][k];
      float r0 = sR[m][0]*w0 + sR[m][1]*w1 + sR[m][2]*w2;
      float r1 = sR[m][3]*w0 + sR[m][4]*w1 + sR[m][5]*w2;
      float r2 = sR[m][6]*w0 + sR[m][7]*w1 + sR[m][8]*w2;
      float t0 = sT[m][0], t1 = sT[m][1], t2 = sT[m][2];
      den += lk;
      Xn0 += r0 + t0*lk; Xn1 += r1 + t1*lk; Xn2 += r2 + t2*lk;
      S2  += sH[m][k] + 2.f*(t0*r0+t1*r1+t2*r2) + sTn[m]*lk;
    }
    float x0, x1, x2;
    if (iter > 1) { float inv = 1.f/den; x0=Xn0*inv; x1=Xn1*inv; x2=Xn2*inv; }
    else          { x0=sX[k][0]; x1=sX[k][1]; x2=sX[k][2]; }
    float wn = S2 + (x0*x0+x1*x1+x2*x2)*den - 2.f*(x0*Xn0+x1*Xn1+x2*Xn2);
    float qn = 3.f*den / (wn + 3.f*den*EPSILON_C);
    ws[WS_X + k*3+0]=x0; ws[WS_X + k*3+1]=x1; ws[WS_X + k*3+2]=x2;
    ws[WS_Q + k] = qn;
  }
}

// ---------------------------------------------------------------- final out
__global__ __launch_bounds__(256) void p3_final(const float* __restrict__ Vs,
                                                const float* __restrict__ ws,
                                                float* __restrict__ out) {
  int idx = blockIdx.x*256 + threadIdx.x;
  if (idx < Mv*3*Nv) {
    int m = idx / (3*Nv);
    int r = idx % (3*Nv);
    int d = r / Nv;
    int n = r % Nv;
    float vx = Vs[(size_t)(m*3+0)*Nv + n];
    float vy = Vs[(size_t)(m*3+1)*Nv + n];
    float vz = Vs[(size_t)(m*3+2)*Nv + n];
    out[idx] = fmaf(ws[WS_R+m*9+d*3+0],vx,
               fmaf(ws[WS_R+m*9+d*3+1],vy,
               fmaf(ws[WS_R+m*9+d*3+2],vz, ws[WS_T+m*3+d])));
  } else if (idx < Mv*3*Nv + 72 + 24 + Kv*3) {
    int j = idx - Mv*3*Nv;
    float v;
    if (j < 72)      v = ws[WS_R + j];
    else if (j < 96) v = ws[WS_T + (j-72)];
    else             v = ws[WS_X + (j-96)];
    out[idx] = v;
  }
}

extern "C" void kernel_launch(void* const* d_in, const int* in_sizes, int n_in,
                              void* d_out, int out_size, void* d_ws, size_t ws_size,
                              hipStream_t stream) {
  const float* Vs = (const float*)d_in[0];
  const float* X0 = (const float*)d_in[1];
  const float* Q0 = (const float*)d_in[2];
  float* out = (float*)d_out;
  float* ws  = (float*)d_ws;

  p0_init<<<25, 256, 0, stream>>>(Vs, X0, Q0, ws);
  for (int i = 0; i < NITER; i++) {
    p1_accum<<<Mv*BPM, 256, 0, stream>>>(Vs, ws);
    p2_update<<<1, 256, 0, stream>>>(ws, i);
  }
  int total = Mv*3*Nv + 72 + 24 + Kv*3;
  p3_final<<<(total + 255)/256, 256, 0, stream>>>(Vs, ws, out);
}

// Round 2
// 358.473 us; speedup vs baseline: 1.3706x; 1.3706x over previous
//
#include <hip/hip_runtime.h>
#include <math.h>

#define Mv 8
#define Nv 8192
#define Kv 256
#define BPM 64           // blocks per m in p1 -> 512 blocks total
#define NITER 6
#define EPSILON_C 0.01f
#define GAMMA_C 0.005f

// ws layout (float offsets)
#define WS_R    0        // 72   (M x 3 x 3 row-major)
#define WS_T    72       // 24   (M x 3)
#define WS_X    96       // 768  (K x 3)
#define WS_Q    864      // 256
#define WS_BETA 1120     // 1
#define WS_L    1124     // 2048 (M x K)
#define WS_W    3172     // 6144 (M x 3 x K)  -- raw (no Q scaling)
#define WS_H    9316     // 2048 (M x K)
#define WS_ZERO_N (2048+6144+2048)

// ---- wave-wide sum via DPP (6 VALU-latency ops + readlane; ~50 cyc vs ~720
// for a ds_bpermute butterfly). Returns wave-uniform value. All lanes must be
// active.
__device__ __forceinline__ float wave_red_sum(float x) {
  int v;
  float t;
  v = __builtin_bit_cast(int, x);
  t = __builtin_bit_cast(float, __builtin_amdgcn_update_dpp(0, v, 0x111, 0xf, 0xf, true));  // row_shr:1
  x += t; v = __builtin_bit_cast(int, x);
  t = __builtin_bit_cast(float, __builtin_amdgcn_update_dpp(0, v, 0x112, 0xf, 0xf, true));  // row_shr:2
  x += t; v = __builtin_bit_cast(int, x);
  t = __builtin_bit_cast(float, __builtin_amdgcn_update_dpp(0, v, 0x114, 0xf, 0xf, true));  // row_shr:4
  x += t; v = __builtin_bit_cast(int, x);
  t = __builtin_bit_cast(float, __builtin_amdgcn_update_dpp(0, v, 0x118, 0xf, 0xf, true));  // row_shr:8
  x += t; v = __builtin_bit_cast(int, x);
  t = __builtin_bit_cast(float, __builtin_amdgcn_update_dpp(0, v, 0x142, 0xa, 0xf, false)); // row_bcast:15
  x += t; v = __builtin_bit_cast(int, x);
  t = __builtin_bit_cast(float, __builtin_amdgcn_update_dpp(0, v, 0x143, 0xc, 0xf, false)); // row_bcast:31
  x += t;
  return __builtin_bit_cast(float, __builtin_amdgcn_readlane(__builtin_bit_cast(int, x), 63));
}

// ---------------------------------------------------------------- init
__global__ __launch_bounds__(256) void p0_init(const float* __restrict__ Vs,
                                               const float* __restrict__ X0,
                                               const float* __restrict__ Q0,
                                               float* __restrict__ ws) {
  __shared__ float sred[4];
  int tid = threadIdx.x;
  int b = blockIdx.x;
  int wave = tid >> 6, lane = tid & 63;
  if (b < 24) {
    int m = b / 3, d = b % 3;
    const float* src = Vs + (size_t)(m*3 + d) * Nv;
    float s = 0.f;
    for (int n = tid; n < Nv; n += 256) s += src[n];
    s = wave_red_sum(s);
    if (lane == 0) sred[wave] = s;
    __syncthreads();
    if (tid == 0) {
      float tot = sred[0]+sred[1]+sred[2]+sred[3];
      ws[WS_T + m*3 + d] = -tot / (float)Nv;
    }
    if (d == 0 && tid < 9) {
      ws[WS_R + m*9 + tid] = (tid==0||tid==4||tid==8) ? 1.f : 0.f;
    }
  } else {
    float s = (tid < Kv) ? Q0[tid] : 0.f;
    s = wave_red_sum(s);
    if (lane == 0) sred[wave] = s;
    __syncthreads();
    if (tid == 0) {
      float mq = (sred[0]+sred[1]+sred[2]+sred[3]) / (float)Kv;
      ws[WS_BETA] = GAMMA_C * mq * sqrtf(mq);
    }
    if (tid < Kv) ws[WS_Q + tid] = Q0[tid];
    for (int i = tid; i < Kv*3; i += 256) ws[WS_X + i] = X0[i];
    for (int i = tid; i < WS_ZERO_N; i += 256) ws[WS_L + i] = 0.f;
  }
}

// ------------------------------------------------- big fused pass (per iter)
// One wave per point; lane l owns k in {l, l+64, l+128, l+192}.
// Accumulates L, Wraw, H in registers; block reduce; atomicAdd to ws.
__global__ __launch_bounds__(256) void p1_accum(const float* __restrict__ Vs,
                                                float* __restrict__ ws) {
  __shared__ float sb[4][5][Kv]; // 20 KB
  int m    = blockIdx.x / BPM;
  int blk  = blockIdx.x % BPM;
  int wave = threadIdx.x >> 6;
  int lane = threadIdx.x & 63;
  int wid  = blk*4 + wave;   // 0..255 within this m

  float R00 = ws[WS_R+m*9+0], R01 = ws[WS_R+m*9+1], R02 = ws[WS_R+m*9+2];
  float R10 = ws[WS_R+m*9+3], R11 = ws[WS_R+m*9+4], R12 = ws[WS_R+m*9+5];
  float R20 = ws[WS_R+m*9+6], R21 = ws[WS_R+m*9+7], R22 = ws[WS_R+m*9+8];
  float t0 = ws[WS_T+m*3+0], t1 = ws[WS_T+m*3+1], t2 = ws[WS_T+m*3+2];
  float beta = ws[WS_BETA];

  float kXx[4],kXy[4],kXz[4],kA[4],kB[4],kQ[4],kQ32[4];
  #pragma unroll
  for (int j=0;j<4;j++) {
    int k = lane + 64*j;
    float xx = ws[WS_X+k*3+0], xy = ws[WS_X+k*3+1], xz = ws[WS_X+k*3+2];
    float q  = ws[WS_Q+k];
    kXx[j]=xx; kXy[j]=xy; kXz[j]=xz;
    kA[j]  = -0.5f*q;
    kB[j]  = kA[j]*(xx*xx+xy*xy+xz*xz);
    kQ[j]  = q;
    kQ32[j]= q*sqrtf(q);
  }
  float aL[4]={0,0,0,0}, aWx[4]={0,0,0,0}, aWy[4]={0,0,0,0},
        aWz[4]={0,0,0,0}, aH[4]={0,0,0,0};
  const float* V0 = Vs + (size_t)(m*3+0)*Nv;
  const float* V1 = Vs + (size_t)(m*3+1)*Nv;
  const float* V2 = Vs + (size_t)(m*3+2)*Nv;

  for (int n = wid; n < Nv; n += 256) {
    float vx = V0[n], vy = V1[n], vz = V2[n];
    float px = fmaf(R00,vx, fmaf(R01,vy, fmaf(R02,vz, t0)));
    float py = fmaf(R10,vx, fmaf(R11,vy, fmaf(R12,vz, t1)));
    float pz = fmaf(R20,vx, fmaf(R21,vy, fmaf(R22,vz, t2)));
    float tvn = fmaf(px,px, fmaf(py,py, pz*pz));
    float vn  = fmaf(vx,vx, fmaf(vy,vy, vz*vz));
    float ap[4]; float s = 0.f;
    #pragma unroll
    for (int j=0;j<4;j++) {
      float dot = fmaf(px,kXx[j], fmaf(py,kXy[j], pz*kXz[j]));
      // arg = -0.5*Q*(tvn + xn - 2*dot)
      float arg = fmaf(kQ[j], dot, fmaf(kA[j], tvn, kB[j]));
      float e = __expf(arg)*kQ32[j];
      ap[j] = e; s += e;
    }
    float S = wave_red_sum(s);          // wave-uniform
    float inv = 1.f/(S + beta);
    #pragma unroll
    for (int j=0;j<4;j++) {
      float a = ap[j]*inv;
      aL[j] += a;
      aWx[j] = fmaf(a,vx,aWx[j]);
      aWy[j] = fmaf(a,vy,aWy[j]);
      aWz[j] = fmaf(a,vz,aWz[j]);
      aH[j]  = fmaf(a,vn,aH[j]);
    }
  }
  #pragma unroll
  for (int j=0;j<4;j++) {
    int k = lane + 64*j;
    sb[wave][0][k]=aL[j];  sb[wave][1][k]=aWx[j]; sb[wave][2][k]=aWy[j];
    sb[wave][3][k]=aWz[j]; sb[wave][4][k]=aH[j];
  }
  __syncthreads();
  int k = threadIdx.x;
  float vL  = sb[0][0][k]+sb[1][0][k]+sb[2][0][k]+sb[3][0][k];
  float vWx = sb[0][1][k]+sb[1][1][k]+sb[2][1][k]+sb[3][1][k];
  float vWy = sb[0][2][k]+sb[1][2][k]+sb[2][2][k]+sb[3][2][k];
  float vWz = sb[0][3][k]+sb[1][3][k]+sb[2][3][k]+sb[3][3][k];
  float vH  = sb[0][4][k]+sb[1][4][k]+sb[2][4][k]+sb[3][4][k];
  atomicAdd(&ws[WS_L + m*Kv + k], vL);
  atomicAdd(&ws[WS_W + (m*3+0)*Kv + k], vWx);
  atomicAdd(&ws[WS_W + (m*3+1)*Kv + k], vWy);
  atomicAdd(&ws[WS_W + (m*3+2)*Kv + k], vWz);
  atomicAdd(&ws[WS_H + m*Kv + k], vH);
}

// ---------------------------------------------------------------- 3x3 SVD->R
// NOTE: Jacobi loop is forced rolled (#pragma unroll 1). A fully-unrolled
// fp64 body (div/sqrt expand ~10 instrs each) made ~70KB of straight-line
// code -> I$-fetch-bound single-wave execution (R1: 50us at 0.02% VALUBusy).
__device__ void svd3_rot(const double P[3][3], double R[3][3]) {
  double A[3][3];
  for (int i=0;i<3;i++) for (int j=0;j<3;j++) {
    double s=0; for (int k=0;k<3;k++) s += P[k][i]*P[k][j];
    A[i][j]=s;
  }
  double V[3][3] = {{1,0,0},{0,1,0},{0,0,1}};
  #pragma unroll 1
  for (int it=0; it<18; it++) {
    int r3 = it % 3;
    int p = (r3==2) ? 1 : 0;
    int q = (r3==0) ? 1 : 2;
    double apq = A[p][q];
    if (fabs(apq) >= 1e-300) {
      double tau = (A[q][q]-A[p][p])/(2.0*apq);
      double tt = (tau>=0.0) ? 1.0/(tau + sqrt(1.0+tau*tau))
                             : 1.0/(tau - sqrt(1.0+tau*tau));
      double c = 1.0/sqrt(1.0+tt*tt), s = tt*c;
      #pragma unroll
      for (int k2=0;k2<3;k2++){ double akp=A[k2][p], akq=A[k2][q];
        A[k2][p]=c*akp - s*akq; A[k2][q]=s*akp + c*akq; }
      #pragma unroll
      for (int k2=0;k2<3;k2++){ double apk=A[p][k2], aqk=A[q][k2];
        A[p][k2]=c*apk - s*aqk; A[q][k2]=s*apk + c*aqk; }
      #pragma unroll
      for (int k2=0;k2<3;k2++){ double vkp=V[k2][p], vkq=V[k2][q];
        V[k2][p]=c*vkp - s*vkq; V[k2][q]=s*vkp + c*vkq; }
    }
  }
  double lam[3] = {A[0][0], A[1][1], A[2][2]};
  int idx[3] = {0,1,2};
  for (int i=0;i<2;i++) for (int j=i+1;j<3;j++)
    if (lam[idx[j]] > lam[idx[i]]) { int tmp=idx[i]; idx[i]=idx[j]; idx[j]=tmp; }
  double v[3][3]; // v[c][i] = column c of V
  for (int c=0;c<3;c++) for (int i=0;i<3;i++) v[c][i] = V[i][idx[c]];
  double sv[3];
  for (int c=0;c<3;c++) { double l = lam[idx[c]]; sv[c] = (l>0.0) ? sqrt(l) : 0.0; }
  if (sv[0] <= 1e-150) { // P ~ 0: degenerate, return identity
    for (int i=0;i<3;i++) for (int j=0;j<3;j++) R[i][j] = (i==j)?1.0:0.0;
    return;
  }
  double u[3][3]; int bad2 = 0;
  for (int c=0;c<3;c++) {
    double uc[3];
    for (int i=0;i<3;i++) uc[i] = P[i][0]*v[c][0] + P[i][1]*v[c][1] + P[i][2]*v[c][2];
    if (sv[c] > 1e-12*sv[0]) {
      for (int i=0;i<3;i++) u[c][i] = uc[i]/sv[c];
    } else {
      if (c == 1) { // rank-1: pick any unit vector orthogonal to u0
        double ax[3] = {1,0,0};
        if (fabs(u[0][0]) > 0.9) { ax[0]=0; ax[1]=1; }
        double cx0 = u[0][1]*ax[2]-u[0][2]*ax[1];
        double cx1 = u[0][2]*ax[0]-u[0][0]*ax[2];
        double cx2 = u[0][0]*ax[1]-u[0][1]*ax[0];
        double nn = sqrt(cx0*cx0+cx1*cx1+cx2*cx2);
        u[1][0]=cx0/nn; u[1][1]=cx1/nn; u[1][2]=cx2/nn;
      } else if (c == 2) {
        bad2 = 1;
      }
    }
  }
  if (bad2) {
    double cx0 = u[0][1]*u[1][2]-u[0][2]*u[1][1];
    double cx1 = u[0][2]*u[1][0]-u[0][0]*u[1][2];
    double cx2 = u[0][0]*u[1][1]-u[0][1]*u[1][0];
    double nn = sqrt(cx0*cx0+cx1*cx1+cx2*cx2);
    u[2][0]=cx0/nn; u[2][1]=cx1/nn; u[2][2]=cx2/nn;
  }
  double detU = u[0][0]*(u[1][1]*u[2][2]-u[1][2]*u[2][1])
              - u[1][0]*(u[0][1]*u[2][2]-u[0][2]*u[2][1])
              + u[2][0]*(u[0][1]*u[1][2]-u[0][2]*u[1][1]);
  double detV = v[0][0]*(v[1][1]*v[2][2]-v[1][2]*v[2][1])
              - v[1][0]*(v[0][1]*v[2][2]-v[0][2]*v[2][1])
              + v[2][0]*(v[0][1]*v[1][2]-v[0][2]*v[1][1]);
  double sgn = (detU*detV >= 0.0) ? 1.0 : -1.0;
  for (int i=0;i<3;i++) for (int j=0;j<3;j++)
    R[i][j] = u[0][i]*v[0][j] + u[1][i]*v[1][j] + sgn*u[2][i]*v[2][j];
}

// --------------------------------------- per-iteration small update (1 block)
__global__ __launch_bounds__(256) void p2_update(float* __restrict__ ws, int iter) {
  __shared__ float sL[Mv][Kv];
  __shared__ float sW[Mv][3][Kv];
  __shared__ float sH[Mv][Kv];
  __shared__ float sX[Kv][3];
  __shared__ float sQ[Kv];
  __shared__ float sStats[Mv][16];
  __shared__ float sR[Mv][9];
  __shared__ float sT[Mv][3];
  __shared__ float sTn[Mv];

  int tid = threadIdx.x;
  float* Lg = ws + WS_L;
  for (int i = tid; i < Mv*Kv;   i += 256) ((float*)sL)[i] = Lg[i];
  for (int i = tid; i < Mv*3*Kv; i += 256) ((float*)sW)[i] = (ws+WS_W)[i];
  for (int i = tid; i < Mv*Kv;   i += 256) ((float*)sH)[i] = (ws+WS_H)[i];
  sQ[tid]    = ws[WS_Q + tid];
  sX[tid][0] = ws[WS_X + tid*3+0];
  sX[tid][1] = ws[WS_X + tid*3+1];
  sX[tid][2] = ws[WS_X + tid*3+2];
  __syncthreads();
  // zero accumulators for next p1 (nothing in this kernel reads them again)
  for (int i = tid; i < WS_ZERO_N; i += 256) Lg[i] = 0.f;

  int wave = tid >> 6, lane = tid & 63;
  // ---- stats: wave w handles m = w and m = w+4; lane owns 4 k's.
  #pragma unroll
  for (int pass = 0; pass < 2; pass++) {
    int m = wave + 4*pass;
    float pr[16];
    #pragma unroll
    for (int v2=0; v2<16; v2++) pr[v2] = 0.f;
    #pragma unroll
    for (int j=0;j<4;j++) {
      int k = lane + 64*j;
      float lk = sL[m][k], q = sQ[k];
      float bk = lk*q;
      float w0 = sW[m][0][k]*q, w1 = sW[m][1][k]*q, w2 = sW[m][2][k]*q;
      float x0 = sX[k][0], x1 = sX[k][1], x2 = sX[k][2];
      pr[0]+=bk;  pr[1]=fmaf(bk,x0,pr[1]); pr[2]=fmaf(bk,x1,pr[2]); pr[3]=fmaf(bk,x2,pr[3]);
      pr[4]+=w0;  pr[5]+=w1;    pr[6]+=w2;
      pr[7]=fmaf(w0,x0,pr[7]);  pr[8]=fmaf(w1,x0,pr[8]);  pr[9]=fmaf(w2,x0,pr[9]);
      pr[10]=fmaf(w0,x1,pr[10]); pr[11]=fmaf(w1,x1,pr[11]); pr[12]=fmaf(w2,x1,pr[12]);
      pr[13]=fmaf(w0,x2,pr[13]); pr[14]=fmaf(w1,x2,pr[14]); pr[15]=fmaf(w2,x2,pr[15]);
    }
    float red[16];
    #pragma unroll
    for (int v2=0; v2<16; v2++) red[v2] = wave_red_sum(pr[v2]);
    if (lane == 0) {
      #pragma unroll
      for (int v2=0; v2<16; v2++) sStats[m][v2] = red[v2];
    }
  }
  __syncthreads();
  if (tid < Mv) {
    int m = tid;
    double z = sStats[m][0];
    double mX[3] = {sStats[m][1], sStats[m][2], sStats[m][3]};
    double mW[3] = {sStats[m][4], sStats[m][5], sStats[m][6]};
    double Pm[3][3];
    for (int e=0;e<3;e++) for (int d=0;d<3;d++)
      Pm[e][d] = (double)sStats[m][7+e*3+d] - mX[e]*mW[d]/z;
    double Rm[3][3];
    svd3_rot(Pm, Rm);
    double tm[3];
    for (int i2=0;i2<3;i2++)
      tm[i2] = (mX[i2] - (Rm[i2][0]*mW[0]+Rm[i2][1]*mW[1]+Rm[i2][2]*mW[2]))/z;
    float tn = 0.f;
    for (int i2=0;i2<3;i2++) {
      for (int j2=0;j2<3;j2++) {
        float rv = (float)Rm[i2][j2];
        sR[m][i2*3+j2] = rv; ws[WS_R+m*9+i2*3+j2] = rv;
      }
      float tv = (float)tm[i2];
      sT[m][i2] = tv; ws[WS_T+m*3+i2] = tv;
      tn += tv*tv;
    }
    sTn[m] = tn;
  }
  __syncthreads();
  {
    int k = tid;
    float den = 0.f, Xn0=0.f, Xn1=0.f, Xn2=0.f, S2=0.f;
    #pragma unroll
    for (int m=0;m<Mv;m++) {
      float lk = sL[m][k];
      float w0 = sW[m][0][k], w1 = sW[m][1][k], w2 = sW[m][2][k];
      float r0 = sR[m][0]*w0 + sR[m][1]*w1 + sR[m][2]*w2;
      float r1 = sR[m][3]*w0 + sR[m][4]*w1 + sR[m][5]*w2;
      float r2 = sR[m][6]*w0 + sR[m][7]*w1 + sR[m][8]*w2;
      float t0 = sT[m][0], t1 = sT[m][1], t2 = sT[m][2];
      den += lk;
      Xn0 += r0 + t0*lk; Xn1 += r1 + t1*lk; Xn2 += r2 + t2*lk;
      S2  += sH[m][k] + 2.f*(t0*r0+t1*r1+t2*r2) + sTn[m]*lk;
    }
    float x0, x1, x2;
    if (iter > 1) { float inv = 1.f/den; x0=Xn0*inv; x1=Xn1*inv; x2=Xn2*inv; }
    else          { x0=sX[k][0]; x1=sX[k][1]; x2=sX[k][2]; }
    float wn = S2 + (x0*x0+x1*x1+x2*x2)*den - 2.f*(x0*Xn0+x1*Xn1+x2*Xn2);
    float qn = 3.f*den / (wn + 3.f*den*EPSILON_C);
    ws[WS_X + k*3+0]=x0; ws[WS_X + k*3+1]=x1; ws[WS_X + k*3+2]=x2;
    ws[WS_Q + k] = qn;
  }
}

// ---------------------------------------------------------------- final out
__global__ __launch_bounds__(256) void p3_final(const float* __restrict__ Vs,
                                                const float* __restrict__ ws,
                                                float* __restrict__ out) {
  int idx = blockIdx.x*256 + threadIdx.x;
  if (idx < Mv*3*Nv) {
    int m = idx / (3*Nv);
    int r = idx % (3*Nv);
    int d = r / Nv;
    int n = r % Nv;
    float vx = Vs[(size_t)(m*3+0)*Nv + n];
    float vy = Vs[(size_t)(m*3+1)*Nv + n];
    float vz = Vs[(size_t)(m*3+2)*Nv + n];
    out[idx] = fmaf(ws[WS_R+m*9+d*3+0],vx,
               fmaf(ws[WS_R+m*9+d*3+1],vy,
               fmaf(ws[WS_R+m*9+d*3+2],vz, ws[WS_T+m*3+d])));
  } else if (idx < Mv*3*Nv + 72 + 24 + Kv*3) {
    int j = idx - Mv*3*Nv;
    float v;
    if (j < 72)      v = ws[WS_R + j];
    else if (j < 96) v = ws[WS_T + (j-72)];
    else             v = ws[WS_X + (j-96)];
    out[idx] = v;
  }
}

extern "C" void kernel_launch(void* const* d_in, const int* in_sizes, int n_in,
                              void* d_out, int out_size, void* d_ws, size_t ws_size,
                              hipStream_t stream) {
  const float* Vs = (const float*)d_in[0];
  const float* X0 = (const float*)d_in[1];
  const float* Q0 = (const float*)d_in[2];
  float* out = (float*)d_out;
  float* ws  = (float*)d_ws;

  p0_init<<<25, 256, 0, stream>>>(Vs, X0, Q0, ws);
  for (int i = 0; i < NITER; i++) {
    p1_accum<<<Mv*BPM, 256, 0, stream>>>(Vs, ws);
    p2_update<<<1, 256, 0, stream>>>(ws, i);
  }
  int total = Mv*3*Nv + 72 + 24 + Kv*3;
  p3_final<<<(total + 255)/256, 256, 0, stream>>>(Vs, ws, out);
}

// Round 3
// 274.339 us; speedup vs baseline: 1.7909x; 1.3067x over previous
//
#include <hip/hip_runtime.h>
#include <math.h>

#define Mv 8
#define Nv 8192
#define Kv 256
#define BPM 64           // blocks per m in p1 -> 512 blocks total
#define NITER 6
#define EPSILON_C 0.01f
#define GAMMA_C 0.005f

// ws layout (float offsets)
#define WS_R    0        // 72   (M x 3 x 3 row-major)
#define WS_T    72       // 24   (M x 3)
#define WS_X    96       // 768  (K x 3)
#define WS_Q    864      // 256
#define WS_BETA 1120     // 1
#define WS_L    1124     // 2048 (M x K)
#define WS_W    3172     // 6144 (M x 3 x K)  -- raw (no Q scaling)
#define WS_H    9316     // 2048 (M x K)
#define WS_ZERO_N (2048+6144+2048)

// ---- wave-wide sum via DPP; wave-uniform result. All lanes must be active.
__device__ __forceinline__ float wave_red_sum(float x) {
  int v;
  float t;
  v = __builtin_bit_cast(int, x);
  t = __builtin_bit_cast(float, __builtin_amdgcn_update_dpp(0, v, 0x111, 0xf, 0xf, true));  // row_shr:1
  x += t; v = __builtin_bit_cast(int, x);
  t = __builtin_bit_cast(float, __builtin_amdgcn_update_dpp(0, v, 0x112, 0xf, 0xf, true));  // row_shr:2
  x += t; v = __builtin_bit_cast(int, x);
  t = __builtin_bit_cast(float, __builtin_amdgcn_update_dpp(0, v, 0x114, 0xf, 0xf, true));  // row_shr:4
  x += t; v = __builtin_bit_cast(int, x);
  t = __builtin_bit_cast(float, __builtin_amdgcn_update_dpp(0, v, 0x118, 0xf, 0xf, true));  // row_shr:8
  x += t; v = __builtin_bit_cast(int, x);
  t = __builtin_bit_cast(float, __builtin_amdgcn_update_dpp(0, v, 0x142, 0xa, 0xf, false)); // row_bcast:15
  x += t; v = __builtin_bit_cast(int, x);
  t = __builtin_bit_cast(float, __builtin_amdgcn_update_dpp(0, v, 0x143, 0xc, 0xf, false)); // row_bcast:31
  x += t;
  return __builtin_bit_cast(float, __builtin_amdgcn_readlane(__builtin_bit_cast(int, x), 63));
}

// ---------------------------------------------------------------- init
__global__ __launch_bounds__(256) void p0_init(const float* __restrict__ Vs,
                                               const float* __restrict__ X0,
                                               const float* __restrict__ Q0,
                                               float* __restrict__ ws) {
  __shared__ float sred[4];
  int tid = threadIdx.x;
  int b = blockIdx.x;
  int wave = tid >> 6, lane = tid & 63;
  if (b < 24) {
    int m = b / 3, d = b % 3;
    const float* src = Vs + (size_t)(m*3 + d) * Nv;
    float s = 0.f;
    for (int n = tid; n < Nv; n += 256) s += src[n];
    s = wave_red_sum(s);
    if (lane == 0) sred[wave] = s;
    __syncthreads();
    if (tid == 0) {
      float tot = sred[0]+sred[1]+sred[2]+sred[3];
      ws[WS_T + m*3 + d] = -tot / (float)Nv;
    }
    if (d == 0 && tid < 9) {
      ws[WS_R + m*9 + tid] = (tid==0||tid==4||tid==8) ? 1.f : 0.f;
    }
  } else {
    float s = (tid < Kv) ? Q0[tid] : 0.f;
    s = wave_red_sum(s);
    if (lane == 0) sred[wave] = s;
    __syncthreads();
    if (tid == 0) {
      float mq = (sred[0]+sred[1]+sred[2]+sred[3]) / (float)Kv;
      ws[WS_BETA] = GAMMA_C * mq * sqrtf(mq);
    }
    if (tid < Kv) ws[WS_Q + tid] = Q0[tid];
    for (int i = tid; i < Kv*3; i += 256) ws[WS_X + i] = X0[i];
    for (int i = tid; i < WS_ZERO_N; i += 256) ws[WS_L + i] = 0.f;
  }
}

// ------------------------------------------------- big fused pass (per iter)
__global__ __launch_bounds__(256) void p1_accum(const float* __restrict__ Vs,
                                                float* __restrict__ ws) {
  __shared__ float sb[4][5][Kv]; // 20 KB
  int m    = blockIdx.x / BPM;
  int blk  = blockIdx.x % BPM;
  int wave = threadIdx.x >> 6;
  int lane = threadIdx.x & 63;
  int wid  = blk*4 + wave;   // 0..255 within this m

  float R00 = ws[WS_R+m*9+0], R01 = ws[WS_R+m*9+1], R02 = ws[WS_R+m*9+2];
  float R10 = ws[WS_R+m*9+3], R11 = ws[WS_R+m*9+4], R12 = ws[WS_R+m*9+5];
  float R20 = ws[WS_R+m*9+6], R21 = ws[WS_R+m*9+7], R22 = ws[WS_R+m*9+8];
  float t0 = ws[WS_T+m*3+0], t1 = ws[WS_T+m*3+1], t2 = ws[WS_T+m*3+2];
  float beta = ws[WS_BETA];

  float kXx[4],kXy[4],kXz[4],kA[4],kB[4],kQ[4],kQ32[4];
  #pragma unroll
  for (int j=0;j<4;j++) {
    int k = lane + 64*j;
    float xx = ws[WS_X+k*3+0], xy = ws[WS_X+k*3+1], xz = ws[WS_X+k*3+2];
    float q  = ws[WS_Q+k];
    kXx[j]=xx; kXy[j]=xy; kXz[j]=xz;
    kA[j]  = -0.5f*q;
    kB[j]  = kA[j]*(xx*xx+xy*xy+xz*xz);
    kQ[j]  = q;
    kQ32[j]= q*sqrtf(q);
  }
  float aL[4]={0,0,0,0}, aWx[4]={0,0,0,0}, aWy[4]={0,0,0,0},
        aWz[4]={0,0,0,0}, aH[4]={0,0,0,0};
  const float* V0 = Vs + (size_t)(m*3+0)*Nv;
  const float* V1 = Vs + (size_t)(m*3+1)*Nv;
  const float* V2 = Vs + (size_t)(m*3+2)*Nv;

  for (int n = wid; n < Nv; n += 256) {
    float vx = V0[n], vy = V1[n], vz = V2[n];
    float px = fmaf(R00,vx, fmaf(R01,vy, fmaf(R02,vz, t0)));
    float py = fmaf(R10,vx, fmaf(R11,vy, fmaf(R12,vz, t1)));
    float pz = fmaf(R20,vx, fmaf(R21,vy, fmaf(R22,vz, t2)));
    float tvn = fmaf(px,px, fmaf(py,py, pz*pz));
    float vn  = fmaf(vx,vx, fmaf(vy,vy, vz*vz));
    float ap[4]; float s = 0.f;
    #pragma unroll
    for (int j=0;j<4;j++) {
      float dot = fmaf(px,kXx[j], fmaf(py,kXy[j], pz*kXz[j]));
      float arg = fmaf(kQ[j], dot, fmaf(kA[j], tvn, kB[j]));
      float e = __expf(arg)*kQ32[j];
      ap[j] = e; s += e;
    }
    float S = wave_red_sum(s);          // wave-uniform
    float inv = 1.f/(S + beta);
    #pragma unroll
    for (int j=0;j<4;j++) {
      float a = ap[j]*inv;
      aL[j] += a;
      aWx[j] = fmaf(a,vx,aWx[j]);
      aWy[j] = fmaf(a,vy,aWy[j]);
      aWz[j] = fmaf(a,vz,aWz[j]);
      aH[j]  = fmaf(a,vn,aH[j]);
    }
  }
  #pragma unroll
  for (int j=0;j<4;j++) {
    int k = lane + 64*j;
    sb[wave][0][k]=aL[j];  sb[wave][1][k]=aWx[j]; sb[wave][2][k]=aWy[j];
    sb[wave][3][k]=aWz[j]; sb[wave][4][k]=aH[j];
  }
  __syncthreads();
  int k = threadIdx.x;
  float vL  = sb[0][0][k]+sb[1][0][k]+sb[2][0][k]+sb[3][0][k];
  float vWx = sb[0][1][k]+sb[1][1][k]+sb[2][1][k]+sb[3][1][k];
  float vWy = sb[0][2][k]+sb[1][2][k]+sb[2][2][k]+sb[3][2][k];
  float vWz = sb[0][3][k]+sb[1][3][k]+sb[2][3][k]+sb[3][3][k];
  float vH  = sb[0][4][k]+sb[1][4][k]+sb[2][4][k]+sb[3][4][k];
  atomicAdd(&ws[WS_L + m*Kv + k], vL);
  atomicAdd(&ws[WS_W + (m*3+0)*Kv + k], vWx);
  atomicAdd(&ws[WS_W + (m*3+1)*Kv + k], vWy);
  atomicAdd(&ws[WS_W + (m*3+2)*Kv + k], vWz);
  atomicAdd(&ws[WS_H + m*Kv + k], vH);
}

// ---- one Jacobi rotation on symmetric 3x3, COMPILE-TIME pair. All operands
// are named scalar doubles (NO runtime-indexed arrays -> no scratch spill;
// R1/R2's indexed arrays (lam[idx[j]], A[k][p]) forced private-memory scratch
// with ~600-cyc serialized round-trips -> 50us p2 at 0.02% VALUBusy).
#define JROT(app,aqq,apq,apr,aqr, vp0,vp1,vp2, vq0,vq1,vq2) do {            \
    double tau_ = (aqq - app) / (2.0*apq);                                  \
    double tt_ = 1.0/(fabs(tau_) + sqrt(1.0+tau_*tau_));                    \
    tt_ = (tau_ < 0.0) ? -tt_ : tt_;                                        \
    tt_ = (apq == 0.0) ? 0.0 : tt_;                                         \
    double c_ = 1.0/sqrt(1.0+tt_*tt_), s_ = tt_*c_;                         \
    double papq_ = apq;                                                     \
    app -= tt_*papq_; aqq += tt_*papq_; apq = 0.0;                          \
    double tp_ = apr, tq_ = aqr;                                            \
    apr = c_*tp_ - s_*tq_; aqr = s_*tp_ + c_*tq_;                           \
    tp_=vp0; tq_=vq0; vp0=c_*tp_-s_*tq_; vq0=s_*tp_+c_*tq_;                 \
    tp_=vp1; tq_=vq1; vp1=c_*tp_-s_*tq_; vq1=s_*tp_+c_*tq_;                 \
    tp_=vp2; tq_=vq2; vp2=c_*tp_-s_*tq_; vq2=s_*tp_+c_*tq_;                 \
  } while(0)

#define CSWAP3(la,lb, a0,a1,a2, b0,b1,b2) do {                              \
    if (la < lb) { double t_;                                               \
      t_=la; la=lb; lb=t_; t_=a0; a0=b0; b0=t_;                             \
      t_=a1; a1=b1; b1=t_; t_=a2; a2=b2; b2=t_; }                           \
  } while(0)

// --------------------------------------- per-iteration small update (1 block)
__global__ __launch_bounds__(256) void p2_update(float* __restrict__ ws, int iter) {
  __shared__ float sL[Mv][Kv];
  __shared__ float sW[Mv][3][Kv];
  __shared__ float sH[Mv][Kv];
  __shared__ float sX[Kv][3];
  __shared__ float sQ[Kv];
  __shared__ float sStats[Mv][16];
  __shared__ float sR[Mv][9];
  __shared__ float sT[Mv][3];
  __shared__ float sTn[Mv];

  int tid = threadIdx.x;
  float* Lg = ws + WS_L;
  for (int i = tid; i < Mv*Kv;   i += 256) ((float*)sL)[i] = Lg[i];
  for (int i = tid; i < Mv*3*Kv; i += 256) ((float*)sW)[i] = (ws+WS_W)[i];
  for (int i = tid; i < Mv*Kv;   i += 256) ((float*)sH)[i] = (ws+WS_H)[i];
  sQ[tid]    = ws[WS_Q + tid];
  sX[tid][0] = ws[WS_X + tid*3+0];
  sX[tid][1] = ws[WS_X + tid*3+1];
  sX[tid][2] = ws[WS_X + tid*3+2];
  __syncthreads();
  // zero accumulators for next p1 (nothing in this kernel reads them again)
  for (int i = tid; i < WS_ZERO_N; i += 256) Lg[i] = 0.f;

  int wave = tid >> 6, lane = tid & 63;
  // ---- stats: wave w handles m = w and m = w+4; lane owns 4 k's.
  #pragma unroll
  for (int pass = 0; pass < 2; pass++) {
    int m = wave + 4*pass;
    float pr[16];
    #pragma unroll
    for (int v2=0; v2<16; v2++) pr[v2] = 0.f;
    #pragma unroll
    for (int j=0;j<4;j++) {
      int k = lane + 64*j;
      float lk = sL[m][k], q = sQ[k];
      float bk = lk*q;
      float w0 = sW[m][0][k]*q, w1 = sW[m][1][k]*q, w2 = sW[m][2][k]*q;
      float x0 = sX[k][0], x1 = sX[k][1], x2 = sX[k][2];
      pr[0]+=bk;  pr[1]=fmaf(bk,x0,pr[1]); pr[2]=fmaf(bk,x1,pr[2]); pr[3]=fmaf(bk,x2,pr[3]);
      pr[4]+=w0;  pr[5]+=w1;    pr[6]+=w2;
      pr[7]=fmaf(w0,x0,pr[7]);  pr[8]=fmaf(w1,x0,pr[8]);  pr[9]=fmaf(w2,x0,pr[9]);
      pr[10]=fmaf(w0,x1,pr[10]); pr[11]=fmaf(w1,x1,pr[11]); pr[12]=fmaf(w2,x1,pr[12]);
      pr[13]=fmaf(w0,x2,pr[13]); pr[14]=fmaf(w1,x2,pr[14]); pr[15]=fmaf(w2,x2,pr[15]);
    }
    float red[16];
    #pragma unroll
    for (int v2=0; v2<16; v2++) red[v2] = wave_red_sum(pr[v2]);
    if (lane == 0) {
      #pragma unroll
      for (int v2=0; v2<16; v2++) sStats[m][v2] = red[v2];
    }
  }
  __syncthreads();
  if (tid < Mv) {
    int m = tid;
    double z = sStats[m][0];
    double mX0 = sStats[m][1], mX1 = sStats[m][2], mX2 = sStats[m][3];
    double mW0 = sStats[m][4], mW1 = sStats[m][5], mW2 = sStats[m][6];
    double iz = 1.0/z;
    // P[e][d] = stats[7+e*3+d] - mX[e]*mW[d]/z   (named scalars)
    double P00 = (double)sStats[m][7]  - mX0*mW0*iz;
    double P01 = (double)sStats[m][8]  - mX0*mW1*iz;
    double P02 = (double)sStats[m][9]  - mX0*mW2*iz;
    double P10 = (double)sStats[m][10] - mX1*mW0*iz;
    double P11 = (double)sStats[m][11] - mX1*mW1*iz;
    double P12 = (double)sStats[m][12] - mX1*mW2*iz;
    double P20 = (double)sStats[m][13] - mX2*mW0*iz;
    double P21 = (double)sStats[m][14] - mX2*mW1*iz;
    double P22 = (double)sStats[m][15] - mX2*mW2*iz;

    // S = P^T P (symmetric, 6 entries)
    double a00 = P00*P00 + P10*P10 + P20*P20;
    double a01 = P00*P01 + P10*P11 + P20*P21;
    double a02 = P00*P02 + P10*P12 + P20*P22;
    double a11 = P01*P01 + P11*P11 + P21*P21;
    double a12 = P01*P02 + P11*P12 + P21*P22;
    double a22 = P02*P02 + P12*P12 + P22*P22;
    // V = I
    double v00=1, v01=0, v02=0, v10=0, v11=1, v12=0, v20=0, v21=0, v22=1;
    #pragma unroll 1
    for (int sweep = 0; sweep < 6; sweep++) {
      JROT(a00,a11,a01, a02,a12, v00,v10,v20, v01,v11,v21);  // pair (0,1)
      JROT(a00,a22,a02, a01,a12, v00,v10,v20, v02,v12,v22);  // pair (0,2)
      JROT(a11,a22,a12, a01,a02, v01,v11,v21, v02,v12,v22);  // pair (1,2)
    }
    // eigen-pairs: (l, column of V); sort descending with named-scalar swaps
    double l0 = a00, l1 = a11, l2 = a22;
    CSWAP3(l0,l1, v00,v10,v20, v01,v11,v21);
    CSWAP3(l1,l2, v01,v11,v21, v02,v12,v22);
    CSWAP3(l0,l1, v00,v10,v20, v01,v11,v21);
    // sign of det(P)
    double detP = P00*(P11*P22-P12*P21) - P01*(P10*P22-P12*P20)
                + P02*(P10*P21-P11*P20);
    double s2 = (detP < 0.0) ? -1.0 : 1.0;
    double tiny = 1e-24*l0 + 1e-290;
    double w0i = 1.0/sqrt(fmax(l0,tiny));
    double w1i = 1.0/sqrt(fmax(l1,tiny));
    double w2i = s2/sqrt(fmax(l2,tiny));
    // Msym = V diag(w) V^T  (symmetric)
    double M00 = w0i*v00*v00 + w1i*v01*v01 + w2i*v02*v02;
    double M01 = w0i*v00*v10 + w1i*v01*v11 + w2i*v02*v12;
    double M02 = w0i*v00*v20 + w1i*v01*v21 + w2i*v02*v22;
    double M11 = w0i*v10*v10 + w1i*v11*v11 + w2i*v12*v12;
    double M12 = w0i*v10*v20 + w1i*v11*v21 + w2i*v12*v22;
    double M22 = w0i*v20*v20 + w1i*v21*v21 + w2i*v22*v22;
    // R = P * Msym
    double R00 = P00*M00 + P01*M01 + P02*M02;
    double R01 = P00*M01 + P01*M11 + P02*M12;
    double R02 = P00*M02 + P01*M12 + P02*M22;
    double R10 = P10*M00 + P11*M01 + P12*M02;
    double R11 = P10*M01 + P11*M11 + P12*M12;
    double R12 = P10*M02 + P11*M12 + P12*M22;
    double R20 = P20*M00 + P21*M01 + P22*M02;
    double R21 = P20*M01 + P21*M11 + P22*M12;
    double R22 = P20*M02 + P21*M12 + P22*M22;
    // t = (mX - R*mW)/z ; store R,t
    double tm0 = (mX0 - (R00*mW0 + R01*mW1 + R02*mW2))*iz;
    double tm1 = (mX1 - (R10*mW0 + R11*mW1 + R12*mW2))*iz;
    double tm2 = (mX2 - (R20*mW0 + R21*mW1 + R22*mW2))*iz;
    float f;
    f=(float)R00; sR[m][0]=f; ws[WS_R+m*9+0]=f;
    f=(float)R01; sR[m][1]=f; ws[WS_R+m*9+1]=f;
    f=(float)R02; sR[m][2]=f; ws[WS_R+m*9+2]=f;
    f=(float)R10; sR[m][3]=f; ws[WS_R+m*9+3]=f;
    f=(float)R11; sR[m][4]=f; ws[WS_R+m*9+4]=f;
    f=(float)R12; sR[m][5]=f; ws[WS_R+m*9+5]=f;
    f=(float)R20; sR[m][6]=f; ws[WS_R+m*9+6]=f;
    f=(float)R21; sR[m][7]=f; ws[WS_R+m*9+7]=f;
    f=(float)R22; sR[m][8]=f; ws[WS_R+m*9+8]=f;
    float t0f=(float)tm0, t1f=(float)tm1, t2f=(float)tm2;
    sT[m][0]=t0f; ws[WS_T+m*3+0]=t0f;
    sT[m][1]=t1f; ws[WS_T+m*3+1]=t1f;
    sT[m][2]=t2f; ws[WS_T+m*3+2]=t2f;
    sTn[m] = t0f*t0f + t1f*t1f + t2f*t2f;
  }
  __syncthreads();
  {
    int k = tid;
    float den = 0.f, Xn0=0.f, Xn1=0.f, Xn2=0.f, S2=0.f;
    #pragma unroll
    for (int m=0;m<Mv;m++) {
      float lk = sL[m][k];
      float w0 = sW[m][0][k], w1 = sW[m][1][k], w2 = sW[m][2][k];
      float r0 = sR[m][0]*w0 + sR[m][1]*w1 + sR[m][2]*w2;
      float r1 = sR[m][3]*w0 + sR[m][4]*w1 + sR[m][5]*w2;
      float r2 = sR[m][6]*w0 + sR[m][7]*w1 + sR[m][8]*w2;
      float t0 = sT[m][0], t1 = sT[m][1], t2 = sT[m][2];
      den += lk;
      Xn0 += r0 + t0*lk; Xn1 += r1 + t1*lk; Xn2 += r2 + t2*lk;
      S2  += sH[m][k] + 2.f*(t0*r0+t1*r1+t2*r2) + sTn[m]*lk;
    }
    float x0, x1, x2;
    if (iter > 1) { float inv = 1.f/den; x0=Xn0*inv; x1=Xn1*inv; x2=Xn2*inv; }
    else          { x0=sX[k][0]; x1=sX[k][1]; x2=sX[k][2]; }
    float wn = S2 + (x0*x0+x1*x1+x2*x2)*den - 2.f*(x0*Xn0+x1*Xn1+x2*Xn2);
    float qn = 3.f*den / (wn + 3.f*den*EPSILON_C);
    ws[WS_X + k*3+0]=x0; ws[WS_X + k*3+1]=x1; ws[WS_X + k*3+2]=x2;
    ws[WS_Q + k] = qn;
  }
}

// ---------------------------------------------------------------- final out
__global__ __launch_bounds__(256) void p3_final(const float* __restrict__ Vs,
                                                const float* __restrict__ ws,
                                                float* __restrict__ out) {
  int idx = blockIdx.x*256 + threadIdx.x;
  if (idx < Mv*3*Nv) {
    int m = idx / (3*Nv);
    int r = idx % (3*Nv);
    int d = r / Nv;
    int n = r % Nv;
    float vx = Vs[(size_t)(m*3+0)*Nv + n];
    float vy = Vs[(size_t)(m*3+1)*Nv + n];
    float vz = Vs[(size_t)(m*3+2)*Nv + n];
    out[idx] = fmaf(ws[WS_R+m*9+d*3+0],vx,
               fmaf(ws[WS_R+m*9+d*3+1],vy,
               fmaf(ws[WS_R+m*9+d*3+2],vz, ws[WS_T+m*3+d])));
  } else if (idx < Mv*3*Nv + 72 + 24 + Kv*3) {
    int j = idx - Mv*3*Nv;
    float v;
    if (j < 72)      v = ws[WS_R + j];
    else if (j < 96) v = ws[WS_T + (j-72)];
    else             v = ws[WS_X + (j-96)];
    out[idx] = v;
  }
}

extern "C" void kernel_launch(void* const* d_in, const int* in_sizes, int n_in,
                              void* d_out, int out_size, void* d_ws, size_t ws_size,
                              hipStream_t stream) {
  const float* Vs = (const float*)d_in[0];
  const float* X0 = (const float*)d_in[1];
  const float* Q0 = (const float*)d_in[2];
  float* out = (float*)d_out;
  float* ws  = (float*)d_ws;

  p0_init<<<25, 256, 0, stream>>>(Vs, X0, Q0, ws);
  for (int i = 0; i < NITER; i++) {
    p1_accum<<<Mv*BPM, 256, 0, stream>>>(Vs, ws);
    p2_update<<<1, 256, 0, stream>>>(ws, i);
  }
  int total = Mv*3*Nv + 72 + 24 + Kv*3;
  p3_final<<<(total + 255)/256, 256, 0, stream>>>(Vs, ws, out);
}

// Round 4
// 248.887 us; speedup vs baseline: 1.9741x; 1.1023x over previous
//
#include <hip/hip_runtime.h>
#include <math.h>

#define Mv 8
#define Nv 8192
#define Kv 256
#define BPM 64           // blocks per m in p1 -> 512 blocks total
#define NITER 6
#define EPSILON_C 0.01f
#define GAMMA_C 0.005f

// ws layout (float offsets)
#define WS_R     0        // 72   (M x 3 x 3 row-major)
#define WS_T     72       // 24   (M x 3)
#define WS_X     96       // 768  (K x 3)
#define WS_Q     864      // 256
#define WS_BETA  1120     // 1
#define WS_STATS 1124     // 128  (M x 16) per-m reduced stats
#define WS_L     1252     // 2048 (M x K)
#define WS_W     3300     // 6144 (M x 3 x K)  -- raw (no Q scaling)
#define WS_H     9444     // 2048 (M x K)
#define WS_ZERO_N (128+2048+6144+2048)   // zero from WS_STATS

// ---- wave-wide sum via DPP; wave-uniform result. All lanes must be active.
__device__ __forceinline__ float wave_red_sum(float x) {
  int v;
  float t;
  v = __builtin_bit_cast(int, x);
  t = __builtin_bit_cast(float, __builtin_amdgcn_update_dpp(0, v, 0x111, 0xf, 0xf, true));  // row_shr:1
  x += t; v = __builtin_bit_cast(int, x);
  t = __builtin_bit_cast(float, __builtin_amdgcn_update_dpp(0, v, 0x112, 0xf, 0xf, true));  // row_shr:2
  x += t; v = __builtin_bit_cast(int, x);
  t = __builtin_bit_cast(float, __builtin_amdgcn_update_dpp(0, v, 0x114, 0xf, 0xf, true));  // row_shr:4
  x += t; v = __builtin_bit_cast(int, x);
  t = __builtin_bit_cast(float, __builtin_amdgcn_update_dpp(0, v, 0x118, 0xf, 0xf, true));  // row_shr:8
  x += t; v = __builtin_bit_cast(int, x);
  t = __builtin_bit_cast(float, __builtin_amdgcn_update_dpp(0, v, 0x142, 0xa, 0xf, false)); // row_bcast:15
  x += t; v = __builtin_bit_cast(int, x);
  t = __builtin_bit_cast(float, __builtin_amdgcn_update_dpp(0, v, 0x143, 0xc, 0xf, false)); // row_bcast:31
  x += t;
  return __builtin_bit_cast(float, __builtin_amdgcn_readlane(__builtin_bit_cast(int, x), 63));
}

// ---------------------------------------------------------------- init
__global__ __launch_bounds__(256) void p0_init(const float* __restrict__ Vs,
                                               const float* __restrict__ X0,
                                               const float* __restrict__ Q0,
                                               float* __restrict__ ws) {
  __shared__ float sred[4];
  int tid = threadIdx.x;
  int b = blockIdx.x;
  int wave = tid >> 6, lane = tid & 63;
  if (b < 24) {
    int m = b / 3, d = b % 3;
    const float* src = Vs + (size_t)(m*3 + d) * Nv;
    float s = 0.f;
    for (int n = tid; n < Nv; n += 256) s += src[n];
    s = wave_red_sum(s);
    if (lane == 0) sred[wave] = s;
    __syncthreads();
    if (tid == 0) {
      float tot = sred[0]+sred[1]+sred[2]+sred[3];
      ws[WS_T + m*3 + d] = -tot / (float)Nv;
    }
    if (d == 0 && tid < 9) {
      ws[WS_R + m*9 + tid] = (tid==0||tid==4||tid==8) ? 1.f : 0.f;
    }
  } else {
    float s = (tid < Kv) ? Q0[tid] : 0.f;
    s = wave_red_sum(s);
    if (lane == 0) sred[wave] = s;
    __syncthreads();
    if (tid == 0) {
      float mq = (sred[0]+sred[1]+sred[2]+sred[3]) / (float)Kv;
      ws[WS_BETA] = GAMMA_C * mq * sqrtf(mq);
    }
    if (tid < Kv) ws[WS_Q + tid] = Q0[tid];
    for (int i = tid; i < Kv*3; i += 256) ws[WS_X + i] = X0[i];
    for (int i = tid; i < WS_ZERO_N; i += 256) ws[WS_STATS + i] = 0.f;
  }
}

// ------------------------------------------------- big fused pass (per iter)
// One wave per point; lane l owns k in {l, l+64, l+128, l+192}.
// Accumulates L, Wraw, H in registers; block reduce; atomicAdd to ws.
// ALSO accumulates this block's partial of the 16 per-m stats (linear in
// L/W/H, so per-block partials + atomics == stats of the full sums).
__global__ __launch_bounds__(256) void p1_accum(const float* __restrict__ Vs,
                                                float* __restrict__ ws) {
  __shared__ float sb[4][5][Kv]; // 20 KB
  __shared__ float st4[4][16];
  int m    = blockIdx.x / BPM;
  int blk  = blockIdx.x % BPM;
  int wave = threadIdx.x >> 6;
  int lane = threadIdx.x & 63;
  int wid  = blk*4 + wave;   // 0..255 within this m

  float R00 = ws[WS_R+m*9+0], R01 = ws[WS_R+m*9+1], R02 = ws[WS_R+m*9+2];
  float R10 = ws[WS_R+m*9+3], R11 = ws[WS_R+m*9+4], R12 = ws[WS_R+m*9+5];
  float R20 = ws[WS_R+m*9+6], R21 = ws[WS_R+m*9+7], R22 = ws[WS_R+m*9+8];
  float t0 = ws[WS_T+m*3+0], t1 = ws[WS_T+m*3+1], t2 = ws[WS_T+m*3+2];
  float beta = ws[WS_BETA];

  float kXx[4],kXy[4],kXz[4],kA[4],kB[4],kQ[4],kQ32[4];
  #pragma unroll
  for (int j=0;j<4;j++) {
    int k = lane + 64*j;
    float xx = ws[WS_X+k*3+0], xy = ws[WS_X+k*3+1], xz = ws[WS_X+k*3+2];
    float q  = ws[WS_Q+k];
    kXx[j]=xx; kXy[j]=xy; kXz[j]=xz;
    kA[j]  = -0.5f*q;
    kB[j]  = kA[j]*(xx*xx+xy*xy+xz*xz);
    kQ[j]  = q;
    kQ32[j]= q*sqrtf(q);
  }
  float aL[4]={0,0,0,0}, aWx[4]={0,0,0,0}, aWy[4]={0,0,0,0},
        aWz[4]={0,0,0,0}, aH[4]={0,0,0,0};
  const float* V0 = Vs + (size_t)(m*3+0)*Nv;
  const float* V1 = Vs + (size_t)(m*3+1)*Nv;
  const float* V2 = Vs + (size_t)(m*3+2)*Nv;

  for (int n = wid; n < Nv; n += 256) {
    float vx = V0[n], vy = V1[n], vz = V2[n];
    float px = fmaf(R00,vx, fmaf(R01,vy, fmaf(R02,vz, t0)));
    float py = fmaf(R10,vx, fmaf(R11,vy, fmaf(R12,vz, t1)));
    float pz = fmaf(R20,vx, fmaf(R21,vy, fmaf(R22,vz, t2)));
    float tvn = fmaf(px,px, fmaf(py,py, pz*pz));
    float vn  = fmaf(vx,vx, fmaf(vy,vy, vz*vz));
    float ap[4]; float s = 0.f;
    #pragma unroll
    for (int j=0;j<4;j++) {
      float dot = fmaf(px,kXx[j], fmaf(py,kXy[j], pz*kXz[j]));
      float arg = fmaf(kQ[j], dot, fmaf(kA[j], tvn, kB[j]));
      float e = __expf(arg)*kQ32[j];
      ap[j] = e; s += e;
    }
    float S = wave_red_sum(s);          // wave-uniform
    float inv = 1.f/(S + beta);
    #pragma unroll
    for (int j=0;j<4;j++) {
      float a = ap[j]*inv;
      aL[j] += a;
      aWx[j] = fmaf(a,vx,aWx[j]);
      aWy[j] = fmaf(a,vy,aWy[j]);
      aWz[j] = fmaf(a,vz,aWz[j]);
      aH[j]  = fmaf(a,vn,aH[j]);
    }
  }
  #pragma unroll
  for (int j=0;j<4;j++) {
    int k = lane + 64*j;
    sb[wave][0][k]=aL[j];  sb[wave][1][k]=aWx[j]; sb[wave][2][k]=aWy[j];
    sb[wave][3][k]=aWz[j]; sb[wave][4][k]=aH[j];
  }
  __syncthreads();
  int k = threadIdx.x;
  float vL  = sb[0][0][k]+sb[1][0][k]+sb[2][0][k]+sb[3][0][k];
  float vWx = sb[0][1][k]+sb[1][1][k]+sb[2][1][k]+sb[3][1][k];
  float vWy = sb[0][2][k]+sb[1][2][k]+sb[2][2][k]+sb[3][2][k];
  float vWz = sb[0][3][k]+sb[1][3][k]+sb[2][3][k]+sb[3][3][k];
  float vH  = sb[0][4][k]+sb[1][4][k]+sb[2][4][k]+sb[3][4][k];
  atomicAdd(&ws[WS_L + m*Kv + k], vL);
  atomicAdd(&ws[WS_W + (m*3+0)*Kv + k], vWx);
  atomicAdd(&ws[WS_W + (m*3+1)*Kv + k], vWy);
  atomicAdd(&ws[WS_W + (m*3+2)*Kv + k], vWz);
  atomicAdd(&ws[WS_H + m*Kv + k], vH);

  // ---- block-partial 16 stats for this m (L2-hot reloads of X,Q at k=tid)
  float q  = ws[WS_Q + k];
  float x0 = ws[WS_X + k*3+0], x1 = ws[WS_X + k*3+1], x2 = ws[WS_X + k*3+2];
  float bk = vL*q;
  float sw0 = vWx*q, sw1 = vWy*q, sw2 = vWz*q;
  float pr[16];
  pr[0]=bk;  pr[1]=bk*x0; pr[2]=bk*x1; pr[3]=bk*x2;
  pr[4]=sw0; pr[5]=sw1;   pr[6]=sw2;
  pr[7]=sw0*x0;  pr[8]=sw1*x0;  pr[9]=sw2*x0;
  pr[10]=sw0*x1; pr[11]=sw1*x1; pr[12]=sw2*x1;
  pr[13]=sw0*x2; pr[14]=sw1*x2; pr[15]=sw2*x2;
  float red[16];
  #pragma unroll
  for (int v2=0; v2<16; v2++) red[v2] = wave_red_sum(pr[v2]);
  if (lane == 0) {
    #pragma unroll
    for (int v2=0; v2<16; v2++) st4[wave][v2] = red[v2];
  }
  __syncthreads();
  if (k < 16)
    atomicAdd(&ws[WS_STATS + m*16 + k],
              st4[0][k]+st4[1][k]+st4[2][k]+st4[3][k]);
}

// ---- one Jacobi rotation on symmetric 3x3, COMPILE-TIME pair. All operands
// are named scalar doubles (NO runtime-indexed arrays -> no scratch spill).
#define JROT(app,aqq,apq,apr,aqr, vp0,vp1,vp2, vq0,vq1,vq2) do {            \
    double tau_ = (aqq - app) / (2.0*apq);                                  \
    double tt_ = 1.0/(fabs(tau_) + sqrt(1.0+tau_*tau_));                    \
    tt_ = (tau_ < 0.0) ? -tt_ : tt_;                                        \
    tt_ = (apq == 0.0) ? 0.0 : tt_;                                         \
    double c_ = 1.0/sqrt(1.0+tt_*tt_), s_ = tt_*c_;                         \
    double papq_ = apq;                                                     \
    app -= tt_*papq_; aqq += tt_*papq_; apq = 0.0;                          \
    double tp_ = apr, tq_ = aqr;                                            \
    apr = c_*tp_ - s_*tq_; aqr = s_*tp_ + c_*tq_;                           \
    tp_=vp0; tq_=vq0; vp0=c_*tp_-s_*tq_; vq0=s_*tp_+c_*tq_;                 \
    tp_=vp1; tq_=vq1; vp1=c_*tp_-s_*tq_; vq1=s_*tp_+c_*tq_;                 \
    tp_=vp2; tq_=vq2; vp2=c_*tp_-s_*tq_; vq2=s_*tp_+c_*tq_;                 \
  } while(0)

#define CSWAP3(la,lb, a0,a1,a2, b0,b1,b2) do {                              \
    if (la < lb) { double t_;                                               \
      t_=la; la=lb; lb=t_; t_=a0; a0=b0; b0=t_;                             \
      t_=a1; a1=b1; b1=t_; t_=a2; a2=b2; b2=t_; }                           \
  } while(0)

// --------------------------------------- per-iteration small update (1 block)
// Per-k data (43 floats) preloaded by every thread BEFORE the SVD branch so
// the memory latency hides under the 8-lane fp64 polar solve. No big LDS.
__global__ __launch_bounds__(256) void p2_update(float* __restrict__ ws, int iter) {
  __shared__ float sR[Mv][9];
  __shared__ float sT[Mv][3];
  __shared__ float sTn[Mv];
  int tid = threadIdx.x;
  const int k = tid;

  // ---- independent coalesced preloads (consumed after the barrier)
  float lk[Mv], w0v[Mv], w1v[Mv], w2v[Mv], hk[Mv];
  #pragma unroll
  for (int m=0;m<Mv;m++) {
    lk[m]  = ws[WS_L + m*Kv + k];
    w0v[m] = ws[WS_W + (m*3+0)*Kv + k];
    w1v[m] = ws[WS_W + (m*3+1)*Kv + k];
    w2v[m] = ws[WS_W + (m*3+2)*Kv + k];
    hk[m]  = ws[WS_H + m*Kv + k];
  }
  float xp0 = ws[WS_X + k*3+0], xp1 = ws[WS_X + k*3+1], xp2 = ws[WS_X + k*3+2];

  if (tid < Mv) {
    int m = tid;
    float* st = ws + WS_STATS + m*16;
    float s0=st[0], s1=st[1], s2v=st[2], s3=st[3], s4=st[4], s5=st[5], s6=st[6],
          s7=st[7], s8=st[8], s9=st[9], s10=st[10], s11=st[11], s12=st[12],
          s13=st[13], s14=st[14], s15=st[15];
    // zero stats for next p1's atomics
    st[0]=0;st[1]=0;st[2]=0;st[3]=0;st[4]=0;st[5]=0;st[6]=0;st[7]=0;
    st[8]=0;st[9]=0;st[10]=0;st[11]=0;st[12]=0;st[13]=0;st[14]=0;st[15]=0;

    double z = s0;
    double mX0 = s1, mX1 = s2v, mX2 = s3;
    double mW0 = s4, mW1 = s5, mW2 = s6;
    double iz = 1.0/z;
    double P00 = (double)s7  - mX0*mW0*iz;
    double P01 = (double)s8  - mX0*mW1*iz;
    double P02 = (double)s9  - mX0*mW2*iz;
    double P10 = (double)s10 - mX1*mW0*iz;
    double P11 = (double)s11 - mX1*mW1*iz;
    double P12 = (double)s12 - mX1*mW2*iz;
    double P20 = (double)s13 - mX2*mW0*iz;
    double P21 = (double)s14 - mX2*mW1*iz;
    double P22 = (double)s15 - mX2*mW2*iz;

    // S = P^T P (symmetric)
    double a00 = P00*P00 + P10*P10 + P20*P20;
    double a01 = P00*P01 + P10*P11 + P20*P21;
    double a02 = P00*P02 + P10*P12 + P20*P22;
    double a11 = P01*P01 + P11*P11 + P21*P21;
    double a12 = P01*P02 + P11*P12 + P21*P22;
    double a22 = P02*P02 + P12*P12 + P22*P22;
    double v00=1, v01=0, v02=0, v10=0, v11=1, v12=0, v20=0, v21=0, v22=1;
    #pragma unroll 1
    for (int sweep = 0; sweep < 6; sweep++) {
      JROT(a00,a11,a01, a02,a12, v00,v10,v20, v01,v11,v21);  // pair (0,1)
      JROT(a00,a22,a02, a01,a12, v00,v10,v20, v02,v12,v22);  // pair (0,2)
      JROT(a11,a22,a12, a01,a02, v01,v11,v21, v02,v12,v22);  // pair (1,2)
    }
    double l0 = a00, l1 = a11, l2 = a22;
    CSWAP3(l0,l1, v00,v10,v20, v01,v11,v21);
    CSWAP3(l1,l2, v01,v11,v21, v02,v12,v22);
    CSWAP3(l0,l1, v00,v10,v20, v01,v11,v21);
    double detP = P00*(P11*P22-P12*P21) - P01*(P10*P22-P12*P20)
                + P02*(P10*P21-P11*P20);
    double s2d = (detP < 0.0) ? -1.0 : 1.0;
    double tiny = 1e-24*l0 + 1e-290;
    double w0i = 1.0/sqrt(fmax(l0,tiny));
    double w1i = 1.0/sqrt(fmax(l1,tiny));
    double w2i = s2d/sqrt(fmax(l2,tiny));
    double M00 = w0i*v00*v00 + w1i*v01*v01 + w2i*v02*v02;
    double M01 = w0i*v00*v10 + w1i*v01*v11 + w2i*v02*v12;
    double M02 = w0i*v00*v20 + w1i*v01*v21 + w2i*v02*v22;
    double M11 = w0i*v10*v10 + w1i*v11*v11 + w2i*v12*v12;
    double M12 = w0i*v10*v20 + w1i*v11*v21 + w2i*v12*v22;
    double M22 = w0i*v20*v20 + w1i*v21*v21 + w2i*v22*v22;
    double R00 = P00*M00 + P01*M01 + P02*M02;
    double R01 = P00*M01 + P01*M11 + P02*M12;
    double R02 = P00*M02 + P01*M12 + P02*M22;
    double R10 = P10*M00 + P11*M01 + P12*M02;
    double R11 = P10*M01 + P11*M11 + P12*M12;
    double R12 = P10*M02 + P11*M12 + P12*M22;
    double R20 = P20*M00 + P21*M01 + P22*M02;
    double R21 = P20*M01 + P21*M11 + P22*M12;
    double R22 = P20*M02 + P21*M12 + P22*M22;
    double tm0 = (mX0 - (R00*mW0 + R01*mW1 + R02*mW2))*iz;
    double tm1 = (mX1 - (R10*mW0 + R11*mW1 + R12*mW2))*iz;
    double tm2 = (mX2 - (R20*mW0 + R21*mW1 + R22*mW2))*iz;
    float f;
    f=(float)R00; sR[m][0]=f; ws[WS_R+m*9+0]=f;
    f=(float)R01; sR[m][1]=f; ws[WS_R+m*9+1]=f;
    f=(float)R02; sR[m][2]=f; ws[WS_R+m*9+2]=f;
    f=(float)R10; sR[m][3]=f; ws[WS_R+m*9+3]=f;
    f=(float)R11; sR[m][4]=f; ws[WS_R+m*9+4]=f;
    f=(float)R12; sR[m][5]=f; ws[WS_R+m*9+5]=f;
    f=(float)R20; sR[m][6]=f; ws[WS_R+m*9+6]=f;
    f=(float)R21; sR[m][7]=f; ws[WS_R+m*9+7]=f;
    f=(float)R22; sR[m][8]=f; ws[WS_R+m*9+8]=f;
    float t0f=(float)tm0, t1f=(float)tm1, t2f=(float)tm2;
    sT[m][0]=t0f; ws[WS_T+m*3+0]=t0f;
    sT[m][1]=t1f; ws[WS_T+m*3+1]=t1f;
    sT[m][2]=t2f; ws[WS_T+m*3+2]=t2f;
    sTn[m] = t0f*t0f + t1f*t1f + t2f*t2f;
  }
  __syncthreads();

  // ---- per-k X/Q update from preloaded registers
  float den = 0.f, Xn0=0.f, Xn1=0.f, Xn2=0.f, S2=0.f;
  #pragma unroll
  for (int m=0;m<Mv;m++) {
    float r0 = sR[m][0]*w0v[m] + sR[m][1]*w1v[m] + sR[m][2]*w2v[m];
    float r1 = sR[m][3]*w0v[m] + sR[m][4]*w1v[m] + sR[m][5]*w2v[m];
    float r2 = sR[m][6]*w0v[m] + sR[m][7]*w1v[m] + sR[m][8]*w2v[m];
    float t0 = sT[m][0], t1 = sT[m][1], t2 = sT[m][2];
    den += lk[m];
    Xn0 += r0 + t0*lk[m]; Xn1 += r1 + t1*lk[m]; Xn2 += r2 + t2*lk[m];
    S2  += hk[m] + 2.f*(t0*r0+t1*r1+t2*r2) + sTn[m]*lk[m];
  }
  float x0, x1, x2;
  if (iter > 1) { float inv = 1.f/den; x0=Xn0*inv; x1=Xn1*inv; x2=Xn2*inv; }
  else          { x0=xp0; x1=xp1; x2=xp2; }
  float wn = S2 + (x0*x0+x1*x1+x2*x2)*den - 2.f*(x0*Xn0+x1*Xn1+x2*Xn2);
  float qn = 3.f*den / (wn + 3.f*den*EPSILON_C);
  ws[WS_X + k*3+0]=x0; ws[WS_X + k*3+1]=x1; ws[WS_X + k*3+2]=x2;
  ws[WS_Q + k] = qn;
  // zero L/W/H in place for the next p1 (same addresses we just consumed)
  #pragma unroll
  for (int m=0;m<Mv;m++) {
    ws[WS_L + m*Kv + k] = 0.f;
    ws[WS_W + (m*3+0)*Kv + k] = 0.f;
    ws[WS_W + (m*3+1)*Kv + k] = 0.f;
    ws[WS_W + (m*3+2)*Kv + k] = 0.f;
    ws[WS_H + m*Kv + k] = 0.f;
  }
}

// ---------------------------------------------------------------- final out
__global__ __launch_bounds__(256) void p3_final(const float* __restrict__ Vs,
                                                const float* __restrict__ ws,
                                                float* __restrict__ out) {
  int idx = blockIdx.x*256 + threadIdx.x;
  if (idx < Mv*3*Nv) {
    int m = idx / (3*Nv);
    int r = idx % (3*Nv);
    int d = r / Nv;
    int n = r % Nv;
    float vx = Vs[(size_t)(m*3+0)*Nv + n];
    float vy = Vs[(size_t)(m*3+1)*Nv + n];
    float vz = Vs[(size_t)(m*3+2)*Nv + n];
    out[idx] = fmaf(ws[WS_R+m*9+d*3+0],vx,
               fmaf(ws[WS_R+m*9+d*3+1],vy,
               fmaf(ws[WS_R+m*9+d*3+2],vz, ws[WS_T+m*3+d])));
  } else if (idx < Mv*3*Nv + 72 + 24 + Kv*3) {
    int j = idx - Mv*3*Nv;
    float v;
    if (j < 72)      v = ws[WS_R + j];
    else if (j < 96) v = ws[WS_T + (j-72)];
    else             v = ws[WS_X + (j-96)];
    out[idx] = v;
  }
}

extern "C" void kernel_launch(void* const* d_in, const int* in_sizes, int n_in,
                              void* d_out, int out_size, void* d_ws, size_t ws_size,
                              hipStream_t stream) {
  const float* Vs = (const float*)d_in[0];
  const float* X0 = (const float*)d_in[1];
  const float* Q0 = (const float*)d_in[2];
  float* out = (float*)d_out;
  float* ws  = (float*)d_ws;

  p0_init<<<25, 256, 0, stream>>>(Vs, X0, Q0, ws);
  for (int i = 0; i < NITER; i++) {
    p1_accum<<<Mv*BPM, 256, 0, stream>>>(Vs, ws);
    p2_update<<<1, 256, 0, stream>>>(ws, i);
  }
  int total = Mv*3*Nv + 72 + 24 + Kv*3;
  p3_final<<<(total + 255)/256, 256, 0, stream>>>(Vs, ws, out);
}